// Round 1
// baseline (550.954 us; speedup 1.0000x reference)
//
#include <hip/hip_runtime.h>
#include <stdint.h>

#define NTOK   4096
#define DMODEL 1024
#define HFF    4096
#define NEXP   8
#define BM     128
#define BN     128
#define BK     64
#define SLOTS_PAD 9216   // 8192 + 8*127 rounded up

typedef unsigned int   u32;
typedef unsigned short u16;
typedef u32   u32x4  __attribute__((ext_vector_type(4)));
typedef short s16x8  __attribute__((ext_vector_type(8)));
typedef float f32x16 __attribute__((ext_vector_type(16)));

__device__ __forceinline__ u16 f2bf(float f) {
  u32 u = __builtin_bit_cast(u32, f);
  return (u16)((u + 0x7FFFu + ((u >> 16) & 1u)) >> 16);   // RNE, finite inputs
}
__device__ __forceinline__ float bf2f(u32 lo16) {
  return __builtin_bit_cast(float, lo16 << 16);
}

// ---------------- x fp32 -> bf16 ----------------
__global__ void k_convert_x(const float* __restrict__ x, u16* __restrict__ xb) {
  int i = (blockIdx.x * 256 + threadIdx.x) * 4;
  float4 v = *(const float4*)(x + i);
  uint2 o;
  o.x = (u32)f2bf(v.x) | ((u32)f2bf(v.y) << 16);
  o.y = (u32)f2bf(v.z) | ((u32)f2bf(v.w) << 16);
  *(uint2*)(xb + i) = o;
}

// ---------------- W [K][N] fp32 -> fragment-ordered bf16 LDS-image tiles --------
// Tile (e,nt,kt) is a 16KB image: idx16=(kw*4+n32)*64+lane, 8 bf16 per idx16:
//   value(j) = W[e][kt*64 + kw*16 + 8*(lane>>5) + j][nt*128 + n32*32 + (lane&31)]
__global__ void k_prearrange(const float* __restrict__ W, u32x4* __restrict__ Bp,
                             int K, int N, int NT, int KT) {
  int gid   = blockIdx.x * 256 + threadIdx.x;
  int idx16 = gid & 1023;
  int tile  = gid >> 10;             // (e*NT + nt)*KT + kt
  int kt  = tile % KT; int rem = tile / KT;
  int nt  = rem % NT;  int e   = rem / NT;
  int lane = idx16 & 63;
  int n32  = (idx16 >> 6) & 3;
  int kw   = idx16 >> 8;
  int k = kt * BK + kw * 16 + 8 * (lane >> 5);
  int n = nt * BN + n32 * 32 + (lane & 31);
  const float* src = W + ((size_t)e * K + k) * N + n;
  u32 w[4];
#pragma unroll
  for (int jj = 0; jj < 4; ++jj) {
    u16 lo = f2bf(src[(size_t)(2 * jj + 0) * N]);
    u16 hi = f2bf(src[(size_t)(2 * jj + 1) * N]);
    w[jj] = (u32)lo | ((u32)hi << 16);
  }
  u32x4 o; o[0] = w[0]; o[1] = w[1]; o[2] = w[2]; o[3] = w[3];
  Bp[gid] = o;
}

// ---------------- gating: logits, top-2, softmax(2), counts ----------------
__global__ void k_gating(const float* __restrict__ x, const float* __restrict__ Wg,
                         const float* __restrict__ bg, int* __restrict__ top_idx,
                         float* __restrict__ top_w, int* __restrict__ counts) {
  int t = blockIdx.x, tid = threadIdx.x;
  float acc[NEXP];
#pragma unroll
  for (int e = 0; e < NEXP; ++e) acc[e] = 0.f;
  const float* xr = x + (size_t)t * DMODEL;
  for (int d = tid; d < DMODEL; d += 256) {
    float xv = xr[d];
    const float4* wg = (const float4*)(Wg + d * NEXP);
    float4 a = wg[0], b = wg[1];
    acc[0] += xv * a.x; acc[1] += xv * a.y; acc[2] += xv * a.z; acc[3] += xv * a.w;
    acc[4] += xv * b.x; acc[5] += xv * b.y; acc[6] += xv * b.z; acc[7] += xv * b.w;
  }
#pragma unroll
  for (int e = 0; e < NEXP; ++e)
#pragma unroll
    for (int off = 32; off; off >>= 1) acc[e] += __shfl_down(acc[e], off);
  __shared__ float red[4][NEXP];
  int w = tid >> 6;
  if ((tid & 63) == 0)
    for (int e = 0; e < NEXP; ++e) red[w][e] = acc[e];
  __syncthreads();
  if (tid == 0) {
    float v0 = -1e30f, v1 = -1e30f; int i0 = 0, i1 = 0;
    for (int e = 0; e < NEXP; ++e) {
      float l = red[0][e] + red[1][e] + red[2][e] + red[3][e] + bg[e];
      if (l > v0)      { v1 = v0; i1 = i0; v0 = l; i0 = e; }
      else if (l > v1) { v1 = l; i1 = e; }
    }
    float e1 = expf(v1 - v0);
    float w0 = 1.f / (1.f + e1);
    top_idx[2 * t] = i0; top_idx[2 * t + 1] = i1;
    top_w[2 * t] = w0;   top_w[2 * t + 1] = e1 * w0;
    atomicAdd(&counts[i0], 1); atomicAdd(&counts[i1], 1);
  }
}

// ---------------- padded prefix offsets ----------------
__global__ void k_offsets(const int* __restrict__ counts, int* __restrict__ poffset) {
  if (threadIdx.x == 0 && blockIdx.x == 0) {
    int off = 0;
    for (int e = 0; e < NEXP; ++e) {
      poffset[e] = off;
      off += (counts[e] + BM - 1) / BM * BM;
    }
  }
}

// ---------------- scatter tokens to expert slots ----------------
__global__ void k_scatter(const int* __restrict__ top_idx, const int* __restrict__ poffset,
                          int* __restrict__ cursor, int* __restrict__ tok_of_slot,
                          int* __restrict__ token_slot) {
  int t = blockIdx.x * 256 + threadIdx.x;
  if (t >= NTOK) return;
  for (int k = 0; k < 2; ++k) {
    int e = top_idx[2 * t + k];
    int p = atomicAdd(&cursor[e], 1);
    int slot = poffset[e] + p;
    tok_of_slot[slot] = t;
    token_slot[2 * t + k] = slot;
  }
}

// ---------------- grouped GEMM: C = act(A @ B + bias), bf16 in/out, fp32 acc ----
// A: bf16 rows (gathered via tok_of_slot if non-null), stride a_stride.
// B: fragment-ordered tiles Bp[(e*NT+nt)*KT+kt], 16KB each, linear-copy to LDS.
// 4 waves as 2x2; wave tile 64x64 via 2x2 mfma_f32_32x32x16_bf16 frags.
__global__ __launch_bounds__(256) void k_gemm(
    const u16* __restrict__ Asrc, int a_stride,
    const int* __restrict__ tok_of_slot,
    const u32x4* __restrict__ Bp,
    const float* __restrict__ bias, int Nfull, int NT, int K,
    const int* __restrict__ counts, const int* __restrict__ poffset,
    u16* __restrict__ Cout, int c_stride, int do_gelu)
{
  const int nt = blockIdx.x;
  const int mt = blockIdx.y;
  const int e  = mt >> 5;
  const int lt = mt & 31;
  const int cnt = counts[e];
  if (lt * BM >= cnt) return;                 // dead tile
  const int base_slot = poffset[e] + lt * BM;

  __shared__ u32x4 As[1024];                  // 16KB, fragment-ordered image
  __shared__ u32x4 Bs[1024];                  // 16KB, fragment-ordered image

  const int tid  = threadIdx.x;
  const int lane = tid & 63;
  const int wv   = tid >> 6;
  const int wm   = wv >> 1;
  const int wn   = wv & 1;

  // A staging: thread handles one row-half (row am, k-half ah); 4 b128 chunks/step
  const int am = tid >> 1;
  const int ah = tid & 1;
  const int arow = tok_of_slot ? tok_of_slot[base_slot + am] : (base_slot + am);
  const u32x4* arp = (const u32x4*)(Asrc + (size_t)arow * a_stride) + ah * 4;

  int dstA[4];
#pragma unroll
  for (int i = 0; i < 4; ++i) {
    const int kl = 32 * ah + 8 * i;           // k_local of this chunk
    dstA[i] = (((kl >> 4) << 2) + (am >> 5)) * 64 + (am & 31) + ((kl >> 3) & 1) * 32;
  }

  const int KT = K / BK;
  const u32x4* btile = Bp + (size_t)(e * NT + nt) * KT * 1024;

  f32x16 acc[2][2] = {};

  for (int kt = 0; kt < KT; ++kt) {
    u32x4 ra[4], rb[4];
    const u32x4* ap = arp + kt * 8;           // +64 bf16 per step
    const u32x4* bt = btile + kt * 1024;
#pragma unroll
    for (int i = 0; i < 4; ++i) ra[i] = ap[i];
#pragma unroll
    for (int i = 0; i < 4; ++i) rb[i] = bt[i * 256 + tid];
    __syncthreads();                          // prior compute done before overwrite
#pragma unroll
    for (int i = 0; i < 4; ++i) As[dstA[i]] = ra[i];
#pragma unroll
    for (int i = 0; i < 4; ++i) Bs[i * 256 + tid] = rb[i];
    __syncthreads();
#pragma unroll
    for (int kw = 0; kw < 4; ++kw) {
      const s16x8 a0 = __builtin_bit_cast(s16x8, As[(kw * 4 + 2 * wm + 0) * 64 + lane]);
      const s16x8 a1 = __builtin_bit_cast(s16x8, As[(kw * 4 + 2 * wm + 1) * 64 + lane]);
      const s16x8 b0 = __builtin_bit_cast(s16x8, Bs[(kw * 4 + 2 * wn + 0) * 64 + lane]);
      const s16x8 b1 = __builtin_bit_cast(s16x8, Bs[(kw * 4 + 2 * wn + 1) * 64 + lane]);
      acc[0][0] = __builtin_amdgcn_mfma_f32_32x32x16_bf16(a0, b0, acc[0][0], 0, 0, 0);
      acc[0][1] = __builtin_amdgcn_mfma_f32_32x32x16_bf16(a0, b1, acc[0][1], 0, 0, 0);
      acc[1][0] = __builtin_amdgcn_mfma_f32_32x32x16_bf16(a1, b0, acc[1][0], 0, 0, 0);
      acc[1][1] = __builtin_amdgcn_mfma_f32_32x32x16_bf16(a1, b1, acc[1][1], 0, 0, 0);
    }
  }

  // epilogue: C/D layout col=lane&31, row=(r&3)+8*(r>>2)+4*(lane>>5)  [m74/m101]
  const int rhi = (lane >> 5) * 4;
  const int col = lane & 31;
#pragma unroll
  for (int ni = 0; ni < 2; ++ni) {
    const int n = nt * BN + (2 * wn + ni) * 32 + col;
    const float bv = bias[(size_t)e * Nfull + n];
#pragma unroll
    for (int mi = 0; mi < 2; ++mi) {
#pragma unroll
      for (int r = 0; r < 16; ++r) {
        const int rowl = (2 * wm + mi) * 32 + (r & 3) + ((r >> 2) * 8) + rhi;
        float v = acc[mi][ni][r] + bv;
        if (do_gelu) v = 0.5f * v * (1.0f + erff(v * 0.70710678118654752f));
        Cout[(size_t)(base_slot + rowl) * c_stride + n] = f2bf(v);
      }
    }
  }
}

// ---------------- combine (top-2 weighted) + residual + LayerNorm ----------------
__global__ void k_combine_ln(const float* __restrict__ x, const u16* __restrict__ y,
                             const int* __restrict__ token_slot, const float* __restrict__ top_w,
                             const float* __restrict__ gamma, const float* __restrict__ beta,
                             float* __restrict__ out) {
  int t = blockIdx.x, tid = threadIdx.x;
  int s0 = token_slot[2 * t], s1 = token_slot[2 * t + 1];
  float w0 = top_w[2 * t], w1 = top_w[2 * t + 1];
  float4 xv = ((const float4*)(x + (size_t)t * DMODEL))[tid];
  uint2 a = ((const uint2*)(y + (size_t)s0 * DMODEL))[tid];
  uint2 b = ((const uint2*)(y + (size_t)s1 * DMODEL))[tid];
  float r0 = xv.x + w0 * bf2f(a.x & 0xffffu) + w1 * bf2f(b.x & 0xffffu);
  float r1 = xv.y + w0 * bf2f(a.x >> 16)     + w1 * bf2f(b.x >> 16);
  float r2 = xv.z + w0 * bf2f(a.y & 0xffffu) + w1 * bf2f(b.y & 0xffffu);
  float r3 = xv.w + w0 * bf2f(a.y >> 16)     + w1 * bf2f(b.y >> 16);
  float s  = r0 + r1 + r2 + r3;
  float sq = r0 * r0 + r1 * r1 + r2 * r2 + r3 * r3;
#pragma unroll
  for (int off = 32; off; off >>= 1) { s += __shfl_down(s, off); sq += __shfl_down(sq, off); }
  __shared__ float rs[4], rq[4];
  __shared__ float mu_s, rsig_s;
  int w = tid >> 6;
  if ((tid & 63) == 0) { rs[w] = s; rq[w] = sq; }
  __syncthreads();
  if (tid == 0) {
    float S = rs[0] + rs[1] + rs[2] + rs[3];
    float Q = rq[0] + rq[1] + rq[2] + rq[3];
    float mu  = S * (1.0f / DMODEL);
    float var = Q * (1.0f / DMODEL) - mu * mu;
    mu_s = mu; rsig_s = rsqrtf(var + 1e-5f);
  }
  __syncthreads();
  float mu = mu_s, rsig = rsig_s;
  float4 gv = ((const float4*)gamma)[tid];
  float4 bv = ((const float4*)beta)[tid];
  float4 o;
  o.x = (r0 - mu) * rsig * gv.x + bv.x;
  o.y = (r1 - mu) * rsig * gv.y + bv.y;
  o.z = (r2 - mu) * rsig * gv.z + bv.z;
  o.w = (r3 - mu) * rsig * gv.w + bv.w;
  ((float4*)(out + (size_t)t * DMODEL))[tid] = o;
}

// ---------------- launch ----------------
extern "C" void kernel_launch(void* const* d_in, const int* in_sizes, int n_in,
                              void* d_out, int out_size, void* d_ws, size_t ws_size,
                              hipStream_t stream) {
  const float* x     = (const float*)d_in[0];
  const float* Wg    = (const float*)d_in[1];
  const float* bg    = (const float*)d_in[2];
  const float* W1    = (const float*)d_in[3];
  const float* b1    = (const float*)d_in[4];
  const float* W2    = (const float*)d_in[5];
  const float* b2    = (const float*)d_in[6];
  const float* gamma = (const float*)d_in[7];
  const float* beta  = (const float*)d_in[8];
  float* out = (float*)d_out;

  // workspace layout (~238 MB total)
  char* ws = (char*)d_ws;
  size_t off = 0;
  auto alloc = [&](size_t bytes) {
    char* p = ws + off;
    off += (bytes + 255) & ~(size_t)255;
    return p;
  };
  u16*   xb   = (u16*)  alloc((size_t)NTOK * DMODEL * 2);        //   8.4 MB
  u32x4* Bp1  = (u32x4*)alloc((size_t)NEXP * DMODEL * HFF * 2);  //  67.1 MB
  u32x4* Bp2  = (u32x4*)alloc((size_t)NEXP * DMODEL * HFF * 2);  //  67.1 MB
  u16*   h    = (u16*)  alloc((size_t)SLOTS_PAD * HFF * 2);      //  75.5 MB
  u16*   yb   = (u16*)  alloc((size_t)SLOTS_PAD * DMODEL * 2);   //  18.9 MB
  int*   meta = (int*)  alloc((size_t)(24 + SLOTS_PAD + 3 * 2 * NTOK) * 4);
  int*   counts      = meta;
  int*   cursor      = counts + 8;
  int*   poffset     = cursor + 8;
  int*   tok_of_slot = poffset + 8;
  int*   token_slot  = tok_of_slot + SLOTS_PAD;
  int*   top_idx     = token_slot + 2 * NTOK;
  float* top_w       = (float*)(top_idx + 2 * NTOK);
  (void)ws_size; (void)in_sizes; (void)n_in; (void)out_size;

  // zero counts/cursor/poffset + tok_of_slot (pad rows -> token 0)
  hipMemsetAsync(meta, 0, (size_t)(24 + SLOTS_PAD) * 4, stream);

  k_convert_x<<<NTOK * DMODEL / 1024, 256, 0, stream>>>(x, xb);

  // W1 [8][1024][4096]: NT=32, KT=16 ; W2 [8][4096][1024]: NT=8, KT=64
  k_prearrange<<<NEXP * (HFF / BN) * (DMODEL / BK) * 4, 256, 0, stream>>>(
      W1, Bp1, DMODEL, HFF, HFF / BN, DMODEL / BK);
  k_prearrange<<<NEXP * (DMODEL / BN) * (HFF / BK) * 4, 256, 0, stream>>>(
      W2, Bp2, HFF, DMODEL, DMODEL / BN, HFF / BK);

  k_gating<<<NTOK, 256, 0, stream>>>(x, Wg, bg, top_idx, top_w, counts);
  k_offsets<<<1, 1, 0, stream>>>(counts, poffset);
  k_scatter<<<NTOK / 256, 256, 0, stream>>>(top_idx, poffset, cursor, tok_of_slot, token_slot);

  dim3 g1(HFF / BN, NEXP * 32);     // 32 x 256 blocks, dead tiles early-exit
  k_gemm<<<g1, 256, 0, stream>>>(xb, DMODEL, tok_of_slot, Bp1, b1, HFF, HFF / BN,
                                 DMODEL, counts, poffset, h, HFF, 1);
  dim3 g2(DMODEL / BN, NEXP * 32);  // 8 x 256 blocks
  k_gemm<<<g2, 256, 0, stream>>>(h, HFF, nullptr, Bp2, b2, DMODEL, DMODEL / BN,
                                 HFF, counts, poffset, yb, DMODEL, 0);

  k_combine_ln<<<NTOK, 256, 0, stream>>>(x, yb, token_slot, top_w, gamma, beta, out);
}